// Round 1
// baseline (341.613 us; speedup 1.0000x reference)
//
#include <hip/hip_runtime.h>
#include <math.h>

#define NB 8
#define NQ 256
#define NK 256
#define DIN 10
#define FDIM 64
#define HIDDEN 256
#define NH 8

// Fourier helpers: reference layout per component is
// [sin(x*1), sin(x*2), ..., sin(x*2^{F-1}), cos(x*1), ..., cos(x*2^{F-1})]
// We compute sin/cos of the base phase and use double-angle identities:
// sin(2x) = 2 sin x cos x ; cos(2x) = 1 - 2 sin^2 x
__device__ __forceinline__ void four4(float x, float* dst) {
    float s1 = __sinf(x), c1 = __cosf(x);
    float s2 = 2.f * s1 * c1, c2 = 1.f - 2.f * s1 * s1;
    float s4 = 2.f * s2 * c2, c4 = 1.f - 2.f * s2 * s2;
    float s8 = 2.f * s4 * c4, c8 = 1.f - 2.f * s4 * s4;
    dst[0] = s1; dst[1] = s2; dst[2] = s4; dst[3] = s8;
    dst[4] = c1; dst[5] = c2; dst[6] = c4; dst[7] = c8;
}
__device__ __forceinline__ void four2(float x, float* dst) {
    float s1 = __sinf(x), c1 = __cosf(x);
    dst[0] = s1; dst[1] = 2.f * s1 * c1;
    dst[2] = c1; dst[3] = 1.f - 2.f * s1 * s1;
}

// block = 256 threads = one (b,i) query row; lane j = key index.
// q-row reads are wave-uniform -> scalar loads; output stores coalesced in j.
// W1 accessed in contiguous wave-uniform 32-float spans -> s_load_dwordx8,
// streaming W1 exactly once per wave (h-tile of 32 keeps pre[] in VGPRs).
__global__ __launch_bounds__(256, 2) void relfeat_kernel(
    const float* __restrict__ q, const float* __restrict__ k,
    const float* __restrict__ W1, const float* __restrict__ b1,
    const float* __restrict__ W2, const float* __restrict__ b2,
    float* __restrict__ out)
{
    const int j = threadIdx.x;
    const int i = blockIdx.x & (NQ - 1);
    const int b = blockIdx.x >> 8;

    const float* qp = q + ((size_t)b * NQ + i) * DIN;
    const float* kp = k + ((size_t)b * NK + j) * DIN;

    const float q0 = qp[0], q3 = qp[3], q4 = qp[4], q5 = qp[5], q6 = qp[6],
                q7 = qp[7], q8 = qp[8];
    const float k0 = kp[0], k3 = kp[3], k4 = kp[4], k5 = kp[5], k6 = kp[6],
                k7 = kp[7], k8 = kp[8];

    const float dpx = k3 - q3, dpy = k4 - q4;
    const float dvx = k5 - q5, dvy = k6 - q6;
    const float dist_sq = dpx * dpx + dpy * dpy;
    const float dist = sqrtf(dist_sq + 1e-6f);
    const float inv_dist = 1.0f / (dist + 0.1f);
    const float inv_d2 = 1.0f / (dist + 1e-6f);
    const float bear_x = dpx * inv_d2, bear_y = dpy * inv_d2;
    const float ata = bear_x * q7 + bear_y * q8;
    const float aspect = bear_x * k7 + bear_y * k8;
    const float dot_dp_dv = dpx * dvx + dpy * dvy;
    const float speed_sq = dvx * dvx + dvy * dvy;
    const float ttca = tanhf(fmaxf(0.f, -dot_dp_dv / (speed_sq + 1e-6f)));
    const float same_team = (q0 == k0) ? 1.f : 0.f;
    const float q_speed = sqrtf(q5 * q5 + q6 * q6);
    const float k_speed = sqrtf(k5 * k5 + k6 * k6);
    const float delta_speed = k_speed - q_speed;

    float feat[FDIM];
    four4(dist,        feat + 0);   // out_dist: [dist, inv_dist], F=4
    four4(inv_dist,    feat + 8);
    four4(ata,         feat + 16);  // out_angle: [ata, aspect], F=4
    four4(aspect,      feat + 24);
    four2(dpx,         feat + 32);  // out_delta: [dpx,dpy,dvx,dvy], F=2
    four2(dpy,         feat + 36);
    four2(dvx,         feat + 40);
    four2(dvy,         feat + 44);
    four2(ttca,        feat + 48);  // out_intercept: [ttca, dist], F=2
    four2(dist,        feat + 52);
    four2(same_team,   feat + 56);  // out_team: [same_team, delta_speed], F=2
    four2(delta_speed, feat + 60);

    float acc[NH];
#pragma unroll
    for (int o = 0; o < NH; ++o) acc[o] = b2[o];

#pragma unroll 1
    for (int h0 = 0; h0 < HIDDEN; h0 += 32) {
        float pre[32];
#pragma unroll
        for (int h = 0; h < 32; ++h) pre[h] = b1[h0 + h];
#pragma unroll 4
        for (int kk = 0; kk < FDIM; ++kk) {
            const float* w = W1 + (size_t)kk * HIDDEN + h0;  // wave-uniform
            const float f = feat[kk];
#pragma unroll
            for (int h = 0; h < 32; ++h) pre[h] = fmaf(f, w[h], pre[h]);
        }
#pragma unroll
        for (int h = 0; h < 32; ++h) {
            const float p = pre[h];
            const float hv = p / (1.f + __expf(-p));  // silu
            const float* w2 = W2 + (size_t)(h0 + h) * NH;  // wave-uniform
#pragma unroll
            for (int o = 0; o < NH; ++o) acc[o] = fmaf(hv, w2[o], acc[o]);
        }
    }

    // out[b, o, i, j]
    const size_t obase = ((size_t)b * NH) * (NQ * NK) + (size_t)i * NK + j;
#pragma unroll
    for (int o = 0; o < NH; ++o) out[obase + (size_t)o * (NQ * NK)] = acc[o];
}

extern "C" void kernel_launch(void* const* d_in, const int* in_sizes, int n_in,
                              void* d_out, int out_size, void* d_ws, size_t ws_size,
                              hipStream_t stream) {
    const float* q  = (const float*)d_in[0];
    const float* k  = (const float*)d_in[1];
    const float* W1 = (const float*)d_in[2];
    const float* b1 = (const float*)d_in[3];
    const float* W2 = (const float*)d_in[4];
    const float* b2 = (const float*)d_in[5];
    float* out = (float*)d_out;

    dim3 grid(NB * NQ);   // 2048 blocks: one per (b, i)
    dim3 block(NK);       // 256 threads: lane = j
    relfeat_kernel<<<grid, block, 0, stream>>>(q, k, W1, b1, W2, b2, out);
}

// Round 2
// 149.078 us; speedup vs baseline: 2.2915x; 2.2915x over previous
//
#include <hip/hip_runtime.h>
#include <math.h>

#define NB 8
#define NQ 256
#define NK 256
#define DIN 10
#define FDIM 64
#define HIDDEN 256
#define NH 8

#define FSTRIDE 72    // shorts per feat row (64 + 8 pad) -> 144 B, 16B-aligned
#define HSTRIDE 264   // shorts per h/w2 row (256 + 8 pad) -> 528 B, 16B-aligned

typedef float f32x4 __attribute__((ext_vector_type(4)));
typedef short bf16x8 __attribute__((ext_vector_type(8)));

// float -> bf16 (round-to-nearest-even), as raw short
__device__ __forceinline__ short f2bf(float f) {
    unsigned u = __float_as_uint(f);
    unsigned r = (u + 0x7fffu + ((u >> 16) & 1u)) >> 16;
    return (short)r;
}

__device__ __forceinline__ void four4(float x, float* dst) {
    float s1 = __sinf(x), c1 = __cosf(x);
    float s2 = 2.f * s1 * c1, c2 = 1.f - 2.f * s1 * s1;
    float s4 = 2.f * s2 * c2, c4 = 1.f - 2.f * s2 * s2;
    float s8 = 2.f * s4 * c4, c8 = 1.f - 2.f * s4 * s4;
    dst[0] = s1; dst[1] = s2; dst[2] = s4; dst[3] = s8;
    dst[4] = c1; dst[5] = c2; dst[6] = c4; dst[7] = c8;
}
__device__ __forceinline__ void four2(float x, float* dst) {
    float s1 = __sinf(x), c1 = __cosf(x);
    dst[0] = s1; dst[1] = 2.f * s1 * c1;
    dst[2] = c1; dst[3] = 1.f - 2.f * s1 * s1;
}

// Block = one (b,i): 256 pairs (j = 0..255), 4 waves.
// MFMA 16x16x32 bf16. A-frag: A[m=lane&15][k=quad*8+e]; B-frag: B[k=quad*8+e][n=lane&15];
// D: row m = quad*4+reg, col n = lane&15.  (verified layouts, m89/m120)
__global__ __launch_bounds__(256, 2) void relfeat_mfma_kernel(
    const float* __restrict__ q, const float* __restrict__ k,
    const float* __restrict__ W1, const float* __restrict__ b1,
    const float* __restrict__ W2, const float* __restrict__ b2,
    float* __restrict__ out)
{
    __shared__ __align__(16) short feat_s[NK * FSTRIDE];   // 36864 B
    __shared__ __align__(16) short h_s[64 * HSTRIDE];      // 33792 B
    __shared__ __align__(16) short w2_s[16 * HSTRIDE];     //  8448 B

    const int t = threadIdx.x;
    const int wave = t >> 6;
    const int lane = t & 63;
    const int lane15 = lane & 15;
    const int quad = lane >> 4;
    const int b = blockIdx.x >> 8;
    const int i = blockIdx.x & (NQ - 1);
    const int j = t;  // pair (key) index within block

    // ---------- Phase 0a: per-pair features -> bf16 -> LDS ----------
    {
        const float* qp = q + ((size_t)b * NQ + i) * DIN;
        const float* kp = k + ((size_t)b * NK + j) * DIN;
        const float q0 = qp[0], q3 = qp[3], q4 = qp[4], q5 = qp[5], q6 = qp[6],
                    q7 = qp[7], q8 = qp[8];
        const float k0 = kp[0], k3 = kp[3], k4 = kp[4], k5 = kp[5], k6 = kp[6],
                    k7 = kp[7], k8 = kp[8];

        const float dpx = k3 - q3, dpy = k4 - q4;
        const float dvx = k5 - q5, dvy = k6 - q6;
        const float dist = sqrtf(dpx * dpx + dpy * dpy + 1e-6f);
        const float inv_dist = 1.0f / (dist + 0.1f);
        const float inv_d2 = 1.0f / (dist + 1e-6f);
        const float bear_x = dpx * inv_d2, bear_y = dpy * inv_d2;
        const float ata = bear_x * q7 + bear_y * q8;
        const float aspect = bear_x * k7 + bear_y * k8;
        const float dot_dp_dv = dpx * dvx + dpy * dvy;
        const float speed_sq = dvx * dvx + dvy * dvy;
        const float ttca = tanhf(fmaxf(0.f, -dot_dp_dv / (speed_sq + 1e-6f)));
        const float same_team = (q0 == k0) ? 1.f : 0.f;
        const float q_speed = sqrtf(q5 * q5 + q6 * q6);
        const float k_speed = sqrtf(k5 * k5 + k6 * k6);
        const float delta_speed = k_speed - q_speed;

        float feat[FDIM];
        four4(dist,        feat + 0);
        four4(inv_dist,    feat + 8);
        four4(ata,         feat + 16);
        four4(aspect,      feat + 24);
        four2(dpx,         feat + 32);
        four2(dpy,         feat + 36);
        four2(dvx,         feat + 40);
        four2(dvy,         feat + 44);
        four2(ttca,        feat + 48);
        four2(dist,        feat + 52);
        four2(same_team,   feat + 56);
        four2(delta_speed, feat + 60);

#pragma unroll
        for (int c8 = 0; c8 < 8; ++c8) {
            bf16x8 v;
#pragma unroll
            for (int e = 0; e < 8; ++e) v[e] = f2bf(feat[c8 * 8 + e]);
            *(bf16x8*)&feat_s[j * FSTRIDE + c8 * 8] = v;
        }
    }

    // ---------- Phase 0b: stage W2^T (o-major) into LDS, zero pad rows ----------
    for (int idx = t; idx < 8 * HSTRIDE; idx += 256) w2_s[8 * HSTRIDE + idx] = 0;
#pragma unroll
    for (int o = 0; o < NH; ++o) w2_s[o * HSTRIDE + t] = f2bf(W2[t * NH + o]);

    // ---------- Phase 0c: W1 B-fragments into registers (one-time, L2-hot) ----------
    const int n0 = wave * 64;  // this wave's 64-hidden slice
    bf16x8 bfrag[4][2];
#pragma unroll
    for (int nt = 0; nt < 4; ++nt) {
#pragma unroll
        for (int ks = 0; ks < 2; ++ks) {
            const float* wp = W1 + (size_t)(ks * 32 + quad * 8) * HIDDEN
                              + (n0 + nt * 16 + lane15);
            bf16x8 v;
#pragma unroll
            for (int e = 0; e < 8; ++e) v[e] = f2bf(wp[(size_t)e * HIDDEN]);
            bfrag[nt][ks] = v;
        }
    }
    float b1f[4];
#pragma unroll
    for (int nt = 0; nt < 4; ++nt) b1f[nt] = b1[n0 + nt * 16 + lane15];
    const float b2v = (lane15 < NH) ? b2[lane15] : 0.f;

    __syncthreads();

    // ---------- Main loop: 4 chunks of 64 pairs ----------
#pragma unroll 1
    for (int m = 0; m < 4; ++m) {
        const int p0 = m * 64;

        // A-fragments for this chunk
        bf16x8 afrag[4][2];
#pragma unroll
        for (int mt = 0; mt < 4; ++mt)
#pragma unroll
            for (int ks = 0; ks < 2; ++ks)
                afrag[mt][ks] = *(const bf16x8*)&feat_s[(p0 + mt * 16 + lane15) * FSTRIDE
                                                        + ks * 32 + quad * 8];

        // GEMM1: feat @ W1 -> pre-activations (wave: 4 M-tiles x 4 N-tiles)
        f32x4 acc[4][4];
#pragma unroll
        for (int mt = 0; mt < 4; ++mt)
#pragma unroll
            for (int nt = 0; nt < 4; ++nt) acc[mt][nt] = (f32x4){0.f, 0.f, 0.f, 0.f};
#pragma unroll
        for (int ks = 0; ks < 2; ++ks)
#pragma unroll
            for (int mt = 0; mt < 4; ++mt)
#pragma unroll
                for (int nt = 0; nt < 4; ++nt)
                    acc[mt][nt] = __builtin_amdgcn_mfma_f32_16x16x32_bf16(
                        afrag[mt][ks], bfrag[nt][ks], acc[mt][nt], 0, 0, 0);

        // bias + silu -> bf16 h into LDS
#pragma unroll
        for (int mt = 0; mt < 4; ++mt) {
#pragma unroll
            for (int nt = 0; nt < 4; ++nt) {
                const int h = n0 + nt * 16 + lane15;
#pragma unroll
                for (int r = 0; r < 4; ++r) {
                    const int pair = mt * 16 + quad * 4 + r;
                    const float p = acc[mt][nt][r] + b1f[nt];
                    const float s = __fdividef(p, 1.f + __expf(-p));
                    h_s[pair * HSTRIDE + h] = f2bf(s);
                }
            }
        }
        __syncthreads();

        // GEMM2: h @ W2 (wave owns 16 pairs; K=256 = 8 steps; N=16, 8 valid)
        const int pw = wave * 16;
        f32x4 acc2 = (f32x4){0.f, 0.f, 0.f, 0.f};
#pragma unroll
        for (int ks = 0; ks < 8; ++ks) {
            bf16x8 ha = *(const bf16x8*)&h_s[(pw + lane15) * HSTRIDE + ks * 32 + quad * 8];
            bf16x8 wb = *(const bf16x8*)&w2_s[lane15 * HSTRIDE + ks * 32 + quad * 8];
            acc2 = __builtin_amdgcn_mfma_f32_16x16x32_bf16(ha, wb, acc2, 0, 0, 0);
        }

        // store: out[b, o, i, j], j = p0 + pw + quad*4 + r  (4 consecutive j per lane)
        if (lane15 < NH) {
            float* op = out + (((size_t)b * NH + lane15) * NQ + i) * NK + (p0 + pw + quad * 4);
            float4 v = make_float4(acc2[0] + b2v, acc2[1] + b2v, acc2[2] + b2v, acc2[3] + b2v);
            *(float4*)op = v;
        }
        __syncthreads();  // protect h_s before next chunk overwrites
    }
}

extern "C" void kernel_launch(void* const* d_in, const int* in_sizes, int n_in,
                              void* d_out, int out_size, void* d_ws, size_t ws_size,
                              hipStream_t stream) {
    const float* q  = (const float*)d_in[0];
    const float* k  = (const float*)d_in[1];
    const float* W1 = (const float*)d_in[2];
    const float* b1 = (const float*)d_in[3];
    const float* W2 = (const float*)d_in[4];
    const float* b2 = (const float*)d_in[5];
    float* out = (float*)d_out;

    dim3 grid(NB * NQ);   // 2048 blocks: one per (b, i)
    dim3 block(NK);       // 256 threads = 4 waves
    relfeat_mfma_kernel<<<grid, block, 0, stream>>>(q, k, W1, b1, W2, b2, out);
}